// Round 1
// baseline (554.122 us; speedup 1.0000x reference)
//
#include <hip/hip_runtime.h>
#include <math.h>

// ---------------------------------------------------------------------------
// MambaCaMix on MI355X — round 0: correctness-first full pipeline, f32.
// B=2, Cin=64, C=128, H=W=64 (L=4096), D_INNER=256, N_STATE=16, DT_RANK=8, K=4
// Scan uses chunked prefix-scan (16 chunks x 256) for occupancy (32 waves/CU).
// Direction sequences are index permutations of x_flat -> never materialize xs.
// ---------------------------------------------------------------------------

#define DEV __device__ __forceinline__

DEV float sigm_(float x){ return 1.f/(1.f+__expf(-x)); }
DEV float silu_(float x){ return x*sigm_(x); }
DEV float softplus_(float x){ return (x>20.f)? x : log1pf(__expf(x)); }

// scan-step l of direction k reads/writes spatial position pos_dir(k,l)
DEV int pos_dir(int k, int l){
  switch(k&3){
    case 0: return l;
    case 1: return ((l&63)<<6)|(l>>6);
    case 2: return 4095-l;
    default:{ int m=4095-l; return ((m&63)<<6)|(m>>6); }
  }
}

#define MM4x4(av,bv) do{ \
  acc[0][0]=fmaf(av.x,bv.x,acc[0][0]); acc[0][1]=fmaf(av.x,bv.y,acc[0][1]); \
  acc[0][2]=fmaf(av.x,bv.z,acc[0][2]); acc[0][3]=fmaf(av.x,bv.w,acc[0][3]); \
  acc[1][0]=fmaf(av.y,bv.x,acc[1][0]); acc[1][1]=fmaf(av.y,bv.y,acc[1][1]); \
  acc[1][2]=fmaf(av.y,bv.z,acc[1][2]); acc[1][3]=fmaf(av.y,bv.w,acc[1][3]); \
  acc[2][0]=fmaf(av.z,bv.x,acc[2][0]); acc[2][1]=fmaf(av.z,bv.y,acc[2][1]); \
  acc[2][2]=fmaf(av.z,bv.z,acc[2][2]); acc[2][3]=fmaf(av.z,bv.w,acc[2][3]); \
  acc[3][0]=fmaf(av.w,bv.x,acc[3][0]); acc[3][1]=fmaf(av.w,bv.y,acc[3][1]); \
  acc[3][2]=fmaf(av.w,bv.z,acc[3][2]); acc[3][3]=fmaf(av.w,bv.w,acc[3][3]); \
}while(0)

// K1: x1[b,o,p] = sum_c convin_w[o,c]*x[b,c,p] + convin_b[o]   (M=128,N=4096,K=64 per b)
__global__ __launch_bounds__(256) void k_x1(const float* __restrict__ x,
    const float* __restrict__ W, const float* __restrict__ bias, float* __restrict__ x1){
  const int b = blockIdx.z;
  const int m0 = blockIdx.y*64, n0 = blockIdx.x*64;
  __shared__ float As[16][68], Bs[16][68];
  const int tid = threadIdx.x, tx = tid&15, ty = tid>>4;
  float acc[4][4]={};
  const float* Bb = x + (size_t)b*64*4096;
  for (int k0=0;k0<64;k0+=16){
    for (int i=tid;i<64*16;i+=256){ int m=i>>4,k=i&15; As[k][m]=W[(m0+m)*64+(k0+k)]; }
    for (int i=tid;i<16*64;i+=256){ int k=i>>6,n=i&63; Bs[k][n]=Bb[(size_t)(k0+k)*4096+(n0+n)]; }
    __syncthreads();
    #pragma unroll
    for (int k=0;k<16;++k){
      float4 av=*(const float4*)&As[k][ty*4];
      float4 bv=*(const float4*)&Bs[k][tx*4];
      MM4x4(av,bv);
    }
    __syncthreads();
  }
  #pragma unroll
  for (int i=0;i<4;++i){
    int o=m0+ty*4+i; float bs=bias[o];
    float4 v=make_float4(acc[i][0]+bs,acc[i][1]+bs,acc[i][2]+bs,acc[i][3]+bs);
    *(float4*)&x1[(size_t)((b<<7)+o)*4096 + n0+tx*4]=v;
  }
}

// K2: LayerNorm over C=128 -> mln (B*L,128). Tile 128ch x 32pos through LDS.
__global__ __launch_bounds__(256) void k_ln(const float* __restrict__ x1,
    const float* __restrict__ g, const float* __restrict__ be, float* __restrict__ mln){
  const int b=blockIdx.y, p0=blockIdx.x*32;
  __shared__ float tile[128][33];
  __shared__ float red[2][8][32];
  __shared__ float mean_s[32], rstd_s[32];
  const int tid=threadIdx.x;
  for (int i=tid;i<128*32;i+=256){ int o=i>>5,pp=i&31; tile[o][pp]=x1[(size_t)((b<<7)+o)*4096+p0+pp]; }
  __syncthreads();
  {
    int p=tid&31, seg=tid>>5;
    float s=0.f,s2=0.f;
    #pragma unroll
    for (int j=0;j<16;++j){ float v=tile[seg*16+j][p]; s+=v; s2=fmaf(v,v,s2); }
    red[0][seg][p]=s; red[1][seg][p]=s2;
  }
  __syncthreads();
  if (tid<32){
    float ss=0.f,ss2=0.f;
    #pragma unroll
    for (int sg=0;sg<8;++sg){ ss+=red[0][sg][tid]; ss2+=red[1][sg][tid]; }
    float mu=ss*(1.f/128.f), var=ss2*(1.f/128.f)-mu*mu;
    mean_s[tid]=mu; rstd_s[tid]=rsqrtf(var+1e-5f);
  }
  __syncthreads();
  for (int i=tid;i<128*32;i+=256){
    int o=i&127, pp=i>>7;
    float v=(tile[o][pp]-mean_s[pp])*rstd_s[pp]*g[o]+be[o];
    mln[(size_t)(b*4096+p0+pp)*128+o]=v;
  }
}

// K3: xz = mln @ Win^T. cols<256 -> xmpre (B,D,L) transposed store; cols>=256 -> z (B,L,D).
__global__ __launch_bounds__(256) void k_inproj(const float* __restrict__ mln,
    const float* __restrict__ W, float* __restrict__ xmpre, float* __restrict__ z){
  const int m0=blockIdx.y*64, n0=blockIdx.x*64;
  __shared__ float As[16][68], Bs[16][68];
  const int tid=threadIdx.x, tx=tid&15, ty=tid>>4;
  float acc[4][4]={};
  for (int k0=0;k0<128;k0+=16){
    for (int i=tid;i<64*16;i+=256){ int m=i>>4,k=i&15; As[k][m]=mln[(size_t)(m0+m)*128+(k0+k)]; }
    for (int i=tid;i<64*16;i+=256){ int n=i>>4,k=i&15; Bs[k][n]=W[(size_t)(n0+n)*128+(k0+k)]; }
    __syncthreads();
    #pragma unroll
    for (int k=0;k<16;++k){
      float4 av=*(const float4*)&As[k][ty*4];
      float4 bv=*(const float4*)&Bs[k][tx*4];
      MM4x4(av,bv);
    }
    __syncthreads();
  }
  #pragma unroll
  for (int i=0;i<4;++i){
    int row=m0+ty*4+i, b=row>>12, p=row&4095;
    #pragma unroll
    for (int j=0;j<4;++j){
      int col=n0+tx*4+j; float v=acc[i][j];
      if (col<256) xmpre[(size_t)((b<<8)+col)*4096+p]=v;
      else         z[(size_t)((b<<12)+p)*256+(col-256)]=v;
    }
  }
}

// K4: depthwise 3x3 conv (cross-correlation, pad 1) + bias + SiLU -> xflat (B,D,L)
__global__ __launch_bounds__(256) void k_dwconv(const float* __restrict__ xmpre,
    const float* __restrict__ cw, const float* __restrict__ cb, float* __restrict__ xflat){
  const int gidx=blockIdx.x*256+threadIdx.x;           // < B*256*4096
  const int p=gidx&4095, d=(gidx>>12)&255, b=gidx>>20;
  const int h=p>>6, w=p&63;
  const float* src=xmpre+(size_t)((b<<8)+d)*4096;
  float acc=cb[d];
  #pragma unroll
  for (int dh=-1;dh<=1;++dh){
    int hh=h+dh; if ((unsigned)hh>=64u) continue;
    #pragma unroll
    for (int dw=-1;dw<=1;++dw){
      int ww=w+dw; if ((unsigned)ww>=64u) continue;
      acc=fmaf(src[hh*64+ww], cw[d*9+(dh+1)*3+(dw+1)], acc);
    }
  }
  xflat[gidx]=silu_(acc);
}

// K5: proj[b, r=k*40+c, p] = sum_d xpw[r,d]*xflat[b,d,p]. c<8 -> pdt (B,K,8,L); else pbc (B,K,L,32)
__global__ __launch_bounds__(256) void k_proj(const float* __restrict__ xflat,
    const float* __restrict__ xpw, float* __restrict__ pdt, float* __restrict__ pbc){
  const int b=blockIdx.z, m0=blockIdx.y*32, n0=blockIdx.x*64;
  __shared__ float As[16][36], Bs[16][68];
  const int tid=threadIdx.x, tx=tid&15, ty=tid>>4;
  float acc[2][4]={};
  const float* Bb=xflat+(size_t)b*256*4096;
  for (int k0=0;k0<256;k0+=16){
    for (int i=tid;i<32*16;i+=256){ int m=i>>4,k=i&15; As[k][m]=xpw[(size_t)(m0+m)*256+(k0+k)]; }
    for (int i=tid;i<16*64;i+=256){ int k=i>>6,n=i&63; Bs[k][n]=Bb[(size_t)(k0+k)*4096+(n0+n)]; }
    __syncthreads();
    #pragma unroll
    for (int k=0;k<16;++k){
      float2 av=*(const float2*)&As[k][ty*2];
      float4 bv=*(const float4*)&Bs[k][tx*4];
      acc[0][0]=fmaf(av.x,bv.x,acc[0][0]); acc[0][1]=fmaf(av.x,bv.y,acc[0][1]);
      acc[0][2]=fmaf(av.x,bv.z,acc[0][2]); acc[0][3]=fmaf(av.x,bv.w,acc[0][3]);
      acc[1][0]=fmaf(av.y,bv.x,acc[1][0]); acc[1][1]=fmaf(av.y,bv.y,acc[1][1]);
      acc[1][2]=fmaf(av.y,bv.z,acc[1][2]); acc[1][3]=fmaf(av.y,bv.w,acc[1][3]);
    }
    __syncthreads();
  }
  #pragma unroll
  for (int i=0;i<2;++i){
    int r=m0+ty*2+i, kd=r/40, c=r%40;
    #pragma unroll
    for (int j=0;j<4;++j){
      int p=n0+tx*4+j; float v=acc[i][j];
      if (c<8) pdt[(size_t)(((b*4+kd)<<3)+c)*4096+p]=v;
      else     pbc[((size_t)((b*4+kd))*4096+p)*32+(c-8)]=v;
    }
  }
}

// K6: delta[bk,d,l] = softplus(sum_r dtw[k,d,r]*pdt[bk,r,l] + dtb[k,d])
__global__ __launch_bounds__(256) void k_delta(const float* __restrict__ pdt,
    const float* __restrict__ dtw, const float* __restrict__ dtb, float* __restrict__ delta){
  const int bk=blockIdx.z, m0=blockIdx.y*64, n0=blockIdx.x*64;
  const int k=bk&3;
  __shared__ float As[8][68], Bs[8][68];
  const int tid=threadIdx.x, tx=tid&15, ty=tid>>4;
  float acc[4][4]={};
  const float* A=dtw+(size_t)k*2048;
  const float* Bm=pdt+(size_t)bk*8*4096;
  for (int i=tid;i<64*8;i+=256){ int m=i>>3,kk=i&7; As[kk][m]=A[(m0+m)*8+kk]; }
  for (int i=tid;i<8*64;i+=256){ int kk=i>>6,n=i&63; Bs[kk][n]=Bm[(size_t)kk*4096+(n0+n)]; }
  __syncthreads();
  #pragma unroll
  for (int kk=0;kk<8;++kk){
    float4 av=*(const float4*)&As[kk][ty*4];
    float4 bv=*(const float4*)&Bs[kk][tx*4];
    MM4x4(av,bv);
  }
  #pragma unroll
  for (int i=0;i<4;++i){
    int d=m0+ty*4+i; float bias=dtb[(k<<8)+d];
    #pragma unroll
    for (int j=0;j<4;++j){
      int l=n0+tx*4+j;
      delta[(size_t)((bk<<8)+d)*4096+l]=softplus_(acc[i][j]+bias);
    }
  }
}

// K7: scan pass A — per-chunk product P and local h_end (h0=0). lane=(d within dgroup, n).
__global__ __launch_bounds__(256) void k_scanA(const float* __restrict__ delta,
    const float* __restrict__ xflat, const float* __restrict__ pbc,
    const float* __restrict__ A_logs, float* __restrict__ Pc, float* __restrict__ He){
  const int bx=blockIdx.x;
  const int dg=bx&15, ch=(bx>>4)&15, k=(bx>>8)&3, b=bx>>10;
  const int tid=threadIdx.x, n=tid&15, dq=tid>>4;
  const int d=(dg<<4)+dq;
  const float acoef=-__expf(A_logs[(((k<<8)+d)<<4)+n]);
  const float* dp=delta+(size_t)(((b*4+k)<<8)+d)*4096;
  const float* up=xflat+(size_t)((b<<8)+d)*4096;
  const float* bp=pbc+(size_t)(b*4+k)*4096*32;
  float P=1.f, h=0.f;
  const int l0=ch<<8;
  for (int s=0;s<256;++s){
    int l=l0+s;
    float dv=dp[l];
    float u=up[pos_dir(k,l)];
    float bt=bp[(size_t)l*32+n];
    float a=__expf(dv*acoef);
    P*=a;
    h=fmaf(h,a,dv*u*bt);
  }
  int idx=(((b*4+k)<<4)+ch)*4096+(dg<<8)+tid;
  Pc[idx]=P; He[idx]=h;
}

// K8: scan pass B — carry-in per chunk (16-step serial per recurrence).
__global__ __launch_bounds__(256) void k_scanB(const float* __restrict__ Pc,
    const float* __restrict__ He, float* __restrict__ Hin){
  const int gid=blockIdx.x*256+threadIdx.x;   // 32768 = (B*K)*4096
  const int bk=gid>>12, dn=gid&4095;
  float Hp=0.f;
  #pragma unroll
  for (int ch=0;ch<16;++ch){
    int idx=((bk<<4)+ch)*4096+dn;
    Hin[idx]=Hp;
    Hp=fmaf(Hp,Pc[idx],He[idx]);
  }
}

// K9: scan pass C — recompute with carry-in; y = sum_n h*C (shfl-xor over 16 lanes);
// write y + u*Ds to y4[b][pos][k][d] (position-major => coalesced 64B per dgroup-step).
__global__ __launch_bounds__(256) void k_scanC(const float* __restrict__ delta,
    const float* __restrict__ xflat, const float* __restrict__ pbc,
    const float* __restrict__ A_logs, const float* __restrict__ Ds,
    const float* __restrict__ Hin, float* __restrict__ y4){
  const int bx=blockIdx.x;
  const int dg=bx&15, ch=(bx>>4)&15, k=(bx>>8)&3, b=bx>>10;
  const int tid=threadIdx.x, n=tid&15, dq=tid>>4;
  const int d=(dg<<4)+dq;
  const float acoef=-__expf(A_logs[(((k<<8)+d)<<4)+n]);
  const float dsv=Ds[(k<<8)+d];
  const float* dp=delta+(size_t)(((b*4+k)<<8)+d)*4096;
  const float* up=xflat+(size_t)((b<<8)+d)*4096;
  const float* bp=pbc+(size_t)(b*4+k)*4096*32;
  const int idx=(((b*4+k)<<4)+ch)*4096+(dg<<8)+tid;
  float h=Hin[idx];
  const int l0=ch<<8;
  for (int s=0;s<256;++s){
    int l=l0+s;
    float dv=dp[l];
    int pos=pos_dir(k,l);
    float u=up[pos];
    float bt=bp[(size_t)l*32+n];
    float ct=bp[(size_t)l*32+16+n];
    float a=__expf(dv*acoef);
    h=fmaf(h,a,dv*u*bt);
    float y=h*ct;
    y+=__shfl_xor(y,1); y+=__shfl_xor(y,2); y+=__shfl_xor(y,4); y+=__shfl_xor(y,8);
    if (n==0){
      y4[((size_t)((b<<12)+pos)*4+k)*256+d]=y+u*dsv;
    }
  }
}

// K10: sum 4 directions, LayerNorm(256), gate with silu(z) -> yg (B,L,256)
__global__ __launch_bounds__(256) void k_outnorm(const float* __restrict__ y4,
    const float* __restrict__ g, const float* __restrict__ be,
    const float* __restrict__ z, float* __restrict__ yg){
  const int bp=blockIdx.x, d=threadIdx.x;
  const float* base=y4+(size_t)bp*1024;
  float v=base[d]+base[256+d]+base[512+d]+base[768+d];
  float s=v, s2=v*v;
  #pragma unroll
  for (int m=1;m<64;m<<=1){ s+=__shfl_xor(s,m); s2+=__shfl_xor(s2,m); }
  __shared__ float rs[4], rs2[4];
  if ((d&63)==0){ rs[d>>6]=s; rs2[d>>6]=s2; }
  __syncthreads();
  float S=rs[0]+rs[1]+rs[2]+rs[3], S2=rs2[0]+rs2[1]+rs2[2]+rs2[3];
  float mu=S*(1.f/256.f), var=S2*(1.f/256.f)-mu*mu, rstd=rsqrtf(var+1e-5f);
  float ln=(v-mu)*rstd*g[d]+be[d];
  float zv=z[(size_t)bp*256+d];
  yg[(size_t)bp*256+d]=ln*silu_(zv);
}

// K11: mamba[b,c,p] = x1[b,c,p] + sum_d Wout[c,d]*yg[b,p,d]
__global__ __launch_bounds__(256) void k_outproj(const float* __restrict__ yg,
    const float* __restrict__ W, const float* __restrict__ x1, float* __restrict__ mamba){
  const int b=blockIdx.z, m0=blockIdx.y*64, n0=blockIdx.x*64;
  __shared__ float As[16][68], Bs[16][68];
  const int tid=threadIdx.x, tx=tid&15, ty=tid>>4;
  float acc[4][4]={};
  const float* Yb=yg+(size_t)(b<<12)*256;
  for (int k0=0;k0<256;k0+=16){
    for (int i=tid;i<64*16;i+=256){ int m=i>>4,k=i&15; As[k][m]=W[(size_t)(m0+m)*256+(k0+k)]; }
    for (int i=tid;i<64*16;i+=256){ int n=i>>4,k=i&15; Bs[k][n]=Yb[(size_t)(n0+n)*256+(k0+k)]; }
    __syncthreads();
    #pragma unroll
    for (int k=0;k<16;++k){
      float4 av=*(const float4*)&As[k][ty*4];
      float4 bv=*(const float4*)&Bs[k][tx*4];
      MM4x4(av,bv);
    }
    __syncthreads();
  }
  #pragma unroll
  for (int i=0;i<4;++i){
    int c=m0+ty*4+i;
    size_t base=(size_t)((b<<7)+c)*4096 + n0+tx*4;
    float4 xv=*(const float4*)&x1[base];
    float4 v=make_float4(acc[i][0]+xv.x,acc[i][1]+xv.y,acc[i][2]+xv.z,acc[i][3]+xv.w);
    *(float4*)&mamba[base]=v;
  }
}

// K12: per (b,c): sum / sumsq / max over HW
__global__ __launch_bounds__(256) void k_stats(const float* __restrict__ mamba, float* __restrict__ stats){
  const int bc=blockIdx.x, tid=threadIdx.x;
  const float* row=mamba+(size_t)bc*4096;
  float s=0.f,s2=0.f,mx=-3.402823466e38f;
  for (int i=tid;i<4096;i+=256){ float v=row[i]; s+=v; s2=fmaf(v,v,s2); mx=fmaxf(mx,v); }
  #pragma unroll
  for (int m=1;m<64;m<<=1){
    s+=__shfl_xor(s,m); s2+=__shfl_xor(s2,m); mx=fmaxf(mx,__shfl_xor(mx,m));
  }
  __shared__ float r0[4],r1[4],r2[4];
  if ((tid&63)==0){ int wv=tid>>6; r0[wv]=s; r1[wv]=s2; r2[wv]=mx; }
  __syncthreads();
  if (tid==0){
    stats[bc*3+0]=r0[0]+r0[1]+r0[2]+r0[3];
    stats[bc*3+1]=r1[0]+r1[1]+r1[2]+r1[3];
    stats[bc*3+2]=fmaxf(fmaxf(r2[0],r2[1]),fmaxf(r2[2],r2[3]));
  }
}

// K13: channel-attention MLP + group-norm stats (single block, 256 threads = (b,c))
__global__ __launch_bounds__(256) void k_att(const float* __restrict__ stats,
    const float* __restrict__ fc1, const float* __restrict__ fc2,
    float* __restrict__ att, float* __restrict__ gstat){
  __shared__ float avg[2][128], mxs[2][128], S1[2][128], S2[2][128], hsum[2][8], attv[2][128];
  const int tid=threadIdx.x, b=tid>>7, c=tid&127;
  float s1=stats[tid*3], s2=stats[tid*3+1], m=stats[tid*3+2];
  avg[b][c]=s1*(1.f/4096.f); mxs[b][c]=m; S1[b][c]=s1; S2[b][c]=s2;
  __syncthreads();
  if (tid<16){
    int bb=tid>>3, i=tid&7;
    float ha=0.f,hm=0.f;
    for (int cc=0;cc<128;++cc){ float w=fc1[i*128+cc]; ha=fmaf(w,avg[bb][cc],ha); hm=fmaf(w,mxs[bb][cc],hm); }
    hsum[bb][i]=fmaxf(ha,0.f)+fmaxf(hm,0.f);   // relu(h_avg)+relu(h_max); fc2 is linear
  }
  __syncthreads();
  float sacc=0.f;
  #pragma unroll
  for (int i=0;i<8;++i) sacc=fmaf(fc2[c*8+i],hsum[b][i],sacc);
  float a=sigm_(sacc);
  attv[b][c]=a; att[tid]=a;
  __syncthreads();
  if (tid<4){
    int bb=tid>>1, gp=tid&1;
    float sum1=0.f,sum2=0.f;
    for (int cc=0;cc<64;++cc){
      int c2=gp*64+cc; float av=attv[bb][c2];
      sum1=fmaf(av,S1[bb][c2],sum1);
      sum2=fmaf(av*av,S2[bb][c2],sum2);
    }
    const float inv=1.f/(64.f*4096.f);
    float mu=sum1*inv, ex2=sum2*inv, var=ex2-mu*mu;
    gstat[tid*2]=mu; gstat[tid*2+1]=rsqrtf(var+1e-5f);
  }
}

// K14: out = silu(groupnorm(mamba*att)*gn_g+gn_b) + x1
__global__ __launch_bounds__(256) void k_final(const float* __restrict__ mamba,
    const float* __restrict__ x1, const float* __restrict__ att,
    const float* __restrict__ gstat, const float* __restrict__ gg,
    const float* __restrict__ gb, float* __restrict__ out){
  const int idx=blockIdx.x*256+threadIdx.x;     // < B*C*L = 1048576
  const int c=(idx>>12)&127, b=idx>>19;
  const int grp=(b<<1)+(c>>6);
  float v=mamba[idx]*att[(b<<7)+c];
  float vn=(v-gstat[grp*2])*gstat[grp*2+1]*gg[c]+gb[c];
  out[idx]=silu_(vn)+x1[idx];
}

extern "C" void kernel_launch(void* const* d_in, const int* in_sizes, int n_in,
                              void* d_out, int out_size, void* d_ws, size_t ws_size,
                              hipStream_t stream){
  (void)in_sizes; (void)n_in; (void)out_size; (void)ws_size;
  const float* x        =(const float*)d_in[0];
  const float* convin_w =(const float*)d_in[1];
  const float* convin_b =(const float*)d_in[2];
  const float* ln_g     =(const float*)d_in[3];
  const float* ln_b     =(const float*)d_in[4];
  const float* in_proj_w=(const float*)d_in[5];
  const float* conv_w   =(const float*)d_in[6];
  const float* conv_b   =(const float*)d_in[7];
  const float* x_proj_w =(const float*)d_in[8];
  const float* dt_w     =(const float*)d_in[9];
  const float* dt_b     =(const float*)d_in[10];
  const float* A_logs   =(const float*)d_in[11];
  const float* Ds       =(const float*)d_in[12];
  const float* outnorm_g=(const float*)d_in[13];
  const float* outnorm_b=(const float*)d_in[14];
  const float* out_proj_w=(const float*)d_in[15];
  const float* ca_fc1_w =(const float*)d_in[16];
  const float* ca_fc2_w =(const float*)d_in[17];
  const float* gn_g     =(const float*)d_in[18];
  const float* gn_b     =(const float*)d_in[19];

  float* ws=(float*)d_ws;
  size_t off=0;
  auto alloc=[&](size_t nfloats)->float*{ float* p=ws+off; off+=(nfloats+63)&~(size_t)63; return p; };
  float* x1   =alloc(1048576);   // (B,C,L)
  float* mln  =alloc(1048576);   // (B*L,C)
  float* z    =alloc(2097152);   // (B,L,256)
  float* xmpre=alloc(2097152);   // (B,256,L) pre-dwconv
  float* xflat=alloc(2097152);   // (B,256,L) post dwconv+silu
  float* pdt  =alloc(262144);    // (B,K,8,L)
  float* pbc  =alloc(1048576);   // (B,K,L,32)
  float* delta=alloc(8388608);   // (B,K,256,L)
  float* Pc   =alloc(524288);    // (B*K,16,4096)
  float* He   =alloc(524288);
  float* Hin  =alloc(524288);
  float* y4   =alloc(8388608);   // (B,L,K,256)
  float* yg   =alloc(2097152);   // (B,L,256)
  float* mamba=alloc(1048576);   // (B,C,L)
  float* stats=alloc(768);       // (B*C,3)
  float* att  =alloc(256);       // (B,C)
  float* gstat=alloc(64);        // (B*2, {mu,rstd})

  const dim3 blk(256);
  k_x1     <<<dim3(64,2,2), blk,0,stream>>>(x, convin_w, convin_b, x1);
  k_ln     <<<dim3(128,2),  blk,0,stream>>>(x1, ln_g, ln_b, mln);
  k_inproj <<<dim3(8,128),  blk,0,stream>>>(mln, in_proj_w, xmpre, z);
  k_dwconv <<<dim3(8192),   blk,0,stream>>>(xmpre, conv_w, conv_b, xflat);
  k_proj   <<<dim3(64,5,2), blk,0,stream>>>(xflat, x_proj_w, pdt, pbc);
  k_delta  <<<dim3(64,4,8), blk,0,stream>>>(pdt, dt_w, dt_b, delta);
  k_scanA  <<<dim3(2048),   blk,0,stream>>>(delta, xflat, pbc, A_logs, Pc, He);
  k_scanB  <<<dim3(128),    blk,0,stream>>>(Pc, He, Hin);
  k_scanC  <<<dim3(2048),   blk,0,stream>>>(delta, xflat, pbc, A_logs, Ds, Hin, y4);
  k_outnorm<<<dim3(8192),   blk,0,stream>>>(y4, outnorm_g, outnorm_b, z, yg);
  k_outproj<<<dim3(64,2,2), blk,0,stream>>>(yg, out_proj_w, x1, mamba);
  k_stats  <<<dim3(256),    blk,0,stream>>>(mamba, stats);
  k_att    <<<dim3(1),      blk,0,stream>>>(stats, ca_fc1_w, ca_fc2_w, att, gstat);
  k_final  <<<dim3(4096),   blk,0,stream>>>(mamba, x1, att, gstat, gn_g, gn_b, (float*)d_out);
}

// Round 2
// 365.449 us; speedup vs baseline: 1.5163x; 1.5163x over previous
//
#include <hip/hip_runtime.h>
#include <math.h>

// ---------------------------------------------------------------------------
// MambaCaMix on MI355X — round 1: scan restructured (lane owns 16 n-states),
// (l,d)-major layouts for coalesced scan access. f32 everywhere.
// B=2, Cin=64, C=128, H=W=64 (L=4096), D_INNER=256, N_STATE=16, DT_RANK=8, K=4
// ---------------------------------------------------------------------------

#define DEV __device__ __forceinline__

DEV float sigm_(float x){ return 1.f/(1.f+__expf(-x)); }
DEV float silu_(float x){ return x*sigm_(x); }
DEV float softplus_(float x){ return (x>20.f)? x : log1pf(__expf(x)); }

DEV int pos_dir(int k, int l){
  switch(k&3){
    case 0: return l;
    case 1: return ((l&63)<<6)|(l>>6);
    case 2: return 4095-l;
    default:{ int m=4095-l; return ((m&63)<<6)|(m>>6); }
  }
}

#define MM4x4(av,bv) do{ \
  acc[0][0]=fmaf(av.x,bv.x,acc[0][0]); acc[0][1]=fmaf(av.x,bv.y,acc[0][1]); \
  acc[0][2]=fmaf(av.x,bv.z,acc[0][2]); acc[0][3]=fmaf(av.x,bv.w,acc[0][3]); \
  acc[1][0]=fmaf(av.y,bv.x,acc[1][0]); acc[1][1]=fmaf(av.y,bv.y,acc[1][1]); \
  acc[1][2]=fmaf(av.y,bv.z,acc[1][2]); acc[1][3]=fmaf(av.y,bv.w,acc[1][3]); \
  acc[2][0]=fmaf(av.z,bv.x,acc[2][0]); acc[2][1]=fmaf(av.z,bv.y,acc[2][1]); \
  acc[2][2]=fmaf(av.z,bv.z,acc[2][2]); acc[2][3]=fmaf(av.z,bv.w,acc[2][3]); \
  acc[3][0]=fmaf(av.w,bv.x,acc[3][0]); acc[3][1]=fmaf(av.w,bv.y,acc[3][1]); \
  acc[3][2]=fmaf(av.w,bv.z,acc[3][2]); acc[3][3]=fmaf(av.w,bv.w,acc[3][3]); \
}while(0)

// K1: x1[b,o,p] = sum_c convin_w[o,c]*x[b,c,p] + convin_b[o]
__global__ __launch_bounds__(256) void k_x1(const float* __restrict__ x,
    const float* __restrict__ W, const float* __restrict__ bias, float* __restrict__ x1){
  const int b = blockIdx.z;
  const int m0 = blockIdx.y*64, n0 = blockIdx.x*64;
  __shared__ float As[16][68], Bs[16][68];
  const int tid = threadIdx.x, tx = tid&15, ty = tid>>4;
  float acc[4][4]={};
  const float* Bb = x + (size_t)b*64*4096;
  for (int k0=0;k0<64;k0+=16){
    for (int i=tid;i<64*16;i+=256){ int m=i>>4,k=i&15; As[k][m]=W[(m0+m)*64+(k0+k)]; }
    for (int i=tid;i<16*64;i+=256){ int k=i>>6,n=i&63; Bs[k][n]=Bb[(size_t)(k0+k)*4096+(n0+n)]; }
    __syncthreads();
    #pragma unroll
    for (int k=0;k<16;++k){
      float4 av=*(const float4*)&As[k][ty*4];
      float4 bv=*(const float4*)&Bs[k][tx*4];
      MM4x4(av,bv);
    }
    __syncthreads();
  }
  #pragma unroll
  for (int i=0;i<4;++i){
    int o=m0+ty*4+i; float bs=bias[o];
    float4 v=make_float4(acc[i][0]+bs,acc[i][1]+bs,acc[i][2]+bs,acc[i][3]+bs);
    *(float4*)&x1[(size_t)((b<<7)+o)*4096 + n0+tx*4]=v;
  }
}

// K2: LayerNorm over C=128 -> mln (B*L,128)
__global__ __launch_bounds__(256) void k_ln(const float* __restrict__ x1,
    const float* __restrict__ g, const float* __restrict__ be, float* __restrict__ mln){
  const int b=blockIdx.y, p0=blockIdx.x*32;
  __shared__ float tile[128][33];
  __shared__ float red[2][8][32];
  __shared__ float mean_s[32], rstd_s[32];
  const int tid=threadIdx.x;
  for (int i=tid;i<128*32;i+=256){ int o=i>>5,pp=i&31; tile[o][pp]=x1[(size_t)((b<<7)+o)*4096+p0+pp]; }
  __syncthreads();
  {
    int p=tid&31, seg=tid>>5;
    float s=0.f,s2=0.f;
    #pragma unroll
    for (int j=0;j<16;++j){ float v=tile[seg*16+j][p]; s+=v; s2=fmaf(v,v,s2); }
    red[0][seg][p]=s; red[1][seg][p]=s2;
  }
  __syncthreads();
  if (tid<32){
    float ss=0.f,ss2=0.f;
    #pragma unroll
    for (int sg=0;sg<8;++sg){ ss+=red[0][sg][tid]; ss2+=red[1][sg][tid]; }
    float mu=ss*(1.f/128.f), var=ss2*(1.f/128.f)-mu*mu;
    mean_s[tid]=mu; rstd_s[tid]=rsqrtf(var+1e-5f);
  }
  __syncthreads();
  for (int i=tid;i<128*32;i+=256){
    int o=i&127, pp=i>>7;
    float v=(tile[o][pp]-mean_s[pp])*rstd_s[pp]*g[o]+be[o];
    mln[(size_t)(b*4096+p0+pp)*128+o]=v;
  }
}

// K3: xz = mln @ Win^T. cols<256 -> xmpre_t (B,L,256); cols>=256 -> z (B,L,256)
__global__ __launch_bounds__(256) void k_inproj(const float* __restrict__ mln,
    const float* __restrict__ W, float* __restrict__ xmpre_t, float* __restrict__ z){
  const int m0=blockIdx.y*64, n0=blockIdx.x*64;
  __shared__ float As[16][68], Bs[16][68];
  const int tid=threadIdx.x, tx=tid&15, ty=tid>>4;
  float acc[4][4]={};
  for (int k0=0;k0<128;k0+=16){
    for (int i=tid;i<64*16;i+=256){ int m=i>>4,k=i&15; As[k][m]=mln[(size_t)(m0+m)*128+(k0+k)]; }
    for (int i=tid;i<64*16;i+=256){ int n=i>>4,k=i&15; Bs[k][n]=W[(size_t)(n0+n)*128+(k0+k)]; }
    __syncthreads();
    #pragma unroll
    for (int k=0;k<16;++k){
      float4 av=*(const float4*)&As[k][ty*4];
      float4 bv=*(const float4*)&Bs[k][tx*4];
      MM4x4(av,bv);
    }
    __syncthreads();
  }
  const int col=n0+tx*4;
  #pragma unroll
  for (int i=0;i<4;++i){
    int row=m0+ty*4+i;
    float4 v=make_float4(acc[i][0],acc[i][1],acc[i][2],acc[i][3]);
    if (col<256) *(float4*)&xmpre_t[(size_t)row*256+col]=v;
    else         *(float4*)&z[(size_t)row*256+(col-256)]=v;
  }
}

// K4: depthwise 3x3 conv + bias + SiLU on (b,l,d) layout -> xflat_t (B,L,256)
__global__ __launch_bounds__(256) void k_dwconv(const float* __restrict__ xmpre_t,
    const float* __restrict__ cw, const float* __restrict__ cb, float* __restrict__ xflat_t){
  __shared__ float sw[2304];
  __shared__ float sb[256];
  const int tid=threadIdx.x;
  for (int i=tid;i<2304;i+=256) sw[i]=cw[i];
  sb[tid]=cb[tid];
  __syncthreads();
  const int bp0=blockIdx.x*16;            // over b*4096
  const int b=bp0>>12, p0=bp0&4095;
  const int dq=tid&63, pg=tid>>6;
  const int d0=dq*4;
  float wr[9][4];
  #pragma unroll
  for (int t=0;t<9;++t)
    #pragma unroll
    for (int c=0;c<4;++c) wr[t][c]=sw[(d0+c)*9+t];
  const float4 bias=make_float4(sb[d0],sb[d0+1],sb[d0+2],sb[d0+3]);
  #pragma unroll
  for (int j=0;j<4;++j){
    const int p=p0+pg*4+j;
    const int h=p>>6, w=p&63;
    float4 acc=bias;
    #pragma unroll
    for (int dh=-1;dh<=1;++dh){
      int hh=h+dh; if ((unsigned)hh>=64u) continue;
      #pragma unroll
      for (int dw=-1;dw<=1;++dw){
        int ww=w+dw; if ((unsigned)ww>=64u) continue;
        const int t=(dh+1)*3+(dw+1);
        float4 iv=*(const float4*)&xmpre_t[((size_t)((b<<12)+hh*64+ww))*256+d0];
        acc.x=fmaf(iv.x,wr[t][0],acc.x); acc.y=fmaf(iv.y,wr[t][1],acc.y);
        acc.z=fmaf(iv.z,wr[t][2],acc.z); acc.w=fmaf(iv.w,wr[t][3],acc.w);
      }
    }
    acc.x=silu_(acc.x); acc.y=silu_(acc.y); acc.z=silu_(acc.z); acc.w=silu_(acc.w);
    *(float4*)&xflat_t[((size_t)((b<<12)+p))*256+d0]=acc;
  }
}

// K5: proj(l,r) = sum_d xflat_t[l,d]*xpw[r,d]; c<8 -> pdt (bk,l,8); else pbc (bk,l,32)
__global__ __launch_bounds__(256) void k_proj(const float* __restrict__ xflat_t,
    const float* __restrict__ xpw, float* __restrict__ pdt, float* __restrict__ pbc){
  const int b=blockIdx.z, n0=blockIdx.y*32, m0=blockIdx.x*64;
  __shared__ float As[16][68], Bs[16][36];
  const int tid=threadIdx.x, tx=tid&15, ty=tid>>4;
  float acc[4][2]={};
  for (int k0=0;k0<256;k0+=16){
    for (int i=tid;i<64*16;i+=256){ int m=i>>4,kk=i&15; As[kk][m]=xflat_t[((size_t)((b<<12)+m0+m))*256+k0+kk]; }
    for (int i=tid;i<32*16;i+=256){ int n=i>>4,kk=i&15; Bs[kk][n]=xpw[(size_t)(n0+n)*256+k0+kk]; }
    __syncthreads();
    #pragma unroll
    for (int kk=0;kk<16;++kk){
      float4 av=*(const float4*)&As[kk][ty*4];
      float2 bv=*(const float2*)&Bs[kk][tx*2];
      acc[0][0]=fmaf(av.x,bv.x,acc[0][0]); acc[0][1]=fmaf(av.x,bv.y,acc[0][1]);
      acc[1][0]=fmaf(av.y,bv.x,acc[1][0]); acc[1][1]=fmaf(av.y,bv.y,acc[1][1]);
      acc[2][0]=fmaf(av.z,bv.x,acc[2][0]); acc[2][1]=fmaf(av.z,bv.y,acc[2][1]);
      acc[3][0]=fmaf(av.w,bv.x,acc[3][0]); acc[3][1]=fmaf(av.w,bv.y,acc[3][1]);
    }
    __syncthreads();
  }
  #pragma unroll
  for (int i=0;i<4;++i){
    int l=m0+ty*4+i;
    #pragma unroll
    for (int j=0;j<2;++j){
      int r=n0+tx*2+j, kd=r/40, c=r%40, bk=b*4+kd;
      float v=acc[i][j];
      if (c<8) pdt[((size_t)bk*4096+l)*8+c]=v;
      else     pbc[((size_t)bk*4096+l)*32+(c-8)]=v;
    }
  }
}

// K6: delta_t[bk,l,d] = softplus(sum_r pdt[bk,l,r]*dtw[k,d,r] + dtb[k,d])
__global__ __launch_bounds__(256) void k_delta(const float* __restrict__ pdt,
    const float* __restrict__ dtw, const float* __restrict__ dtb, float* __restrict__ delta_t){
  const int bk=blockIdx.z, n0=blockIdx.y*64, m0=blockIdx.x*64;
  const int k=bk&3;
  __shared__ float As[8][68], Bs[8][68];
  const int tid=threadIdx.x, tx=tid&15, ty=tid>>4;
  float acc[4][4]={};
  for (int i=tid;i<512;i+=256){ int m=i>>3,r=i&7; As[r][m]=pdt[((size_t)bk*4096+m0+m)*8+r]; }
  for (int i=tid;i<512;i+=256){ int n=i>>3,r=i&7; Bs[r][n]=dtw[(size_t)k*2048+(n0+n)*8+r]; }
  __syncthreads();
  #pragma unroll
  for (int r=0;r<8;++r){
    float4 av=*(const float4*)&As[r][ty*4];
    float4 bv=*(const float4*)&Bs[r][tx*4];
    MM4x4(av,bv);
  }
  const float4 bb=*(const float4*)&dtb[(k<<8)+n0+tx*4];
  #pragma unroll
  for (int i=0;i<4;++i){
    int l=m0+ty*4+i;
    float4 v;
    v.x=softplus_(acc[i][0]+bb.x); v.y=softplus_(acc[i][1]+bb.y);
    v.z=softplus_(acc[i][2]+bb.z); v.w=softplus_(acc[i][3]+bb.w);
    *(float4*)&delta_t[((size_t)bk*4096+l)*256+n0+tx*4]=v;
  }
}

// K7: scan pass A — 128 chunks x 32 steps; thread=(b,k,ch,d) owns 16 n-states.
__global__ __launch_bounds__(256) void k_scanA(const float* __restrict__ delta_t,
    const float* __restrict__ xflat_t, const float* __restrict__ pbc,
    const float* __restrict__ A_logs, float* __restrict__ Pc, float* __restrict__ He){
  const int bx=blockIdx.x;                 // ((b*4+k)*128+ch)
  const int ch=bx&127, k=(bx>>7)&3, b=bx>>9, bk=b*4+k;
  const int d=threadIdx.x;
  __shared__ float sbc[1024];              // 32 steps x 32 (B|C)
  for (int i=d;i<1024;i+=256) sbc[i]=pbc[((size_t)bk*4096+(ch<<5))*32+i];
  float acoef[16];
  const float* ap=&A_logs[((k<<8)+d)<<4];
  #pragma unroll
  for (int n=0;n<16;++n) acoef[n]=-__expf(ap[n]);
  __syncthreads();
  float h[16]; float sdv=0.f;
  #pragma unroll
  for (int n=0;n<16;++n) h[n]=0.f;
  const float* dp=delta_t+(size_t)bk*4096*256+d;
  const float* up=xflat_t+((size_t)b<<12)*256+d;
  for (int s=0;s<32;++s){
    const int l=(ch<<5)+s;
    float dv=dp[(size_t)l*256];
    float u =up[(size_t)pos_dir(k,l)*256];
    float dvu=dv*u;
    sdv+=dv;
    #pragma unroll
    for (int n=0;n<16;++n){
      float a=__expf(dv*acoef[n]);
      h[n]=fmaf(h[n],a,dvu*sbc[s*32+n]);
    }
  }
  const size_t obase=(size_t)ch*32768 + ((size_t)bk*256+d)*16;
  #pragma unroll
  for (int n=0;n<16;++n){ Pc[obase+n]=__expf(acoef[n]*sdv); He[obase+n]=h[n]; }
}

// K8: scan pass B — carry across 128 chunks. Hin may alias Pc (read-before-write order).
__global__ __launch_bounds__(256) void k_scanB(const float* Pc, const float* He, float* Hin){
  const int gid=blockIdx.x*256+threadIdx.x;   // 32768 = B*K*D*N
  float Hp=0.f;
  for (int ch=0;ch<128;++ch){
    size_t idx=(size_t)ch*32768+gid;
    float p=Pc[idx], e=He[idx];
    Hin[idx]=Hp;
    Hp=fmaf(Hp,p,e);
  }
}

// K9: scan pass C — recompute with carry-in, y=sum_n h*C, write y+u*Ds to y4 (b,pos,k,d)
__global__ __launch_bounds__(256) void k_scanC(const float* __restrict__ delta_t,
    const float* __restrict__ xflat_t, const float* __restrict__ pbc,
    const float* __restrict__ A_logs, const float* __restrict__ Ds,
    const float* __restrict__ Hin, float* __restrict__ y4){
  const int bx=blockIdx.x;
  const int ch=bx&127, k=(bx>>7)&3, b=bx>>9, bk=b*4+k;
  const int d=threadIdx.x;
  __shared__ float sbc[1024];
  for (int i=d;i<1024;i+=256) sbc[i]=pbc[((size_t)bk*4096+(ch<<5))*32+i];
  float acoef[16];
  const float* ap=&A_logs[((k<<8)+d)<<4];
  #pragma unroll
  for (int n=0;n<16;++n) acoef[n]=-__expf(ap[n]);
  __syncthreads();
  const float dsv=Ds[(k<<8)+d];
  const size_t ibase=(size_t)ch*32768 + ((size_t)bk*256+d)*16;
  float h[16];
  #pragma unroll
  for (int n=0;n<16;++n) h[n]=Hin[ibase+n];
  const float* dp=delta_t+(size_t)bk*4096*256+d;
  const float* up=xflat_t+((size_t)b<<12)*256+d;
  for (int s=0;s<32;++s){
    const int l=(ch<<5)+s;
    float dv=dp[(size_t)l*256];
    const int pos=pos_dir(k,l);
    float u=up[(size_t)pos*256];
    float dvu=dv*u;
    #pragma unroll
    for (int n=0;n<16;++n){
      float a=__expf(dv*acoef[n]);
      h[n]=fmaf(h[n],a,dvu*sbc[s*32+n]);
    }
    float yv[16];
    #pragma unroll
    for (int n=0;n<16;++n) yv[n]=h[n]*sbc[s*32+16+n];
    #pragma unroll
    for (int st=8;st>0;st>>=1)
      #pragma unroll
      for (int n=0;n<st;++n) yv[n]+=yv[n+st];
    y4[((size_t)((b<<12)+pos)*4+k)*256+d]=yv[0]+u*dsv;
  }
}

// K10: sum 4 directions, LayerNorm(256), gate with silu(z) -> yg (B,L,256)
__global__ __launch_bounds__(256) void k_outnorm(const float* __restrict__ y4,
    const float* __restrict__ g, const float* __restrict__ be,
    const float* __restrict__ z, float* __restrict__ yg){
  const int bp=blockIdx.x, d=threadIdx.x;
  const float* base=y4+(size_t)bp*1024;
  float v=base[d]+base[256+d]+base[512+d]+base[768+d];
  float s=v, s2=v*v;
  #pragma unroll
  for (int m=1;m<64;m<<=1){ s+=__shfl_xor(s,m); s2+=__shfl_xor(s2,m); }
  __shared__ float rs[4], rs2[4];
  if ((d&63)==0){ rs[d>>6]=s; rs2[d>>6]=s2; }
  __syncthreads();
  float S=rs[0]+rs[1]+rs[2]+rs[3], S2=rs2[0]+rs2[1]+rs2[2]+rs2[3];
  float mu=S*(1.f/256.f), var=S2*(1.f/256.f)-mu*mu, rstd=rsqrtf(var+1e-5f);
  float ln=(v-mu)*rstd*g[d]+be[d];
  float zv=z[(size_t)bp*256+d];
  yg[(size_t)bp*256+d]=ln*silu_(zv);
}

// K11: mamba[b,c,p] = x1[b,c,p] + sum_d Wout[c,d]*yg[b,p,d]
__global__ __launch_bounds__(256) void k_outproj(const float* __restrict__ yg,
    const float* __restrict__ W, const float* __restrict__ x1, float* __restrict__ mamba){
  const int b=blockIdx.z, m0=blockIdx.y*64, n0=blockIdx.x*64;
  __shared__ float As[16][68], Bs[16][68];
  const int tid=threadIdx.x, tx=tid&15, ty=tid>>4;
  float acc[4][4]={};
  const float* Yb=yg+(size_t)(b<<12)*256;
  for (int k0=0;k0<256;k0+=16){
    for (int i=tid;i<64*16;i+=256){ int m=i>>4,k=i&15; As[k][m]=W[(size_t)(m0+m)*256+(k0+k)]; }
    for (int i=tid;i<64*16;i+=256){ int n=i>>4,k=i&15; Bs[k][n]=Yb[(size_t)(n0+n)*256+(k0+k)]; }
    __syncthreads();
    #pragma unroll
    for (int k=0;k<16;++k){
      float4 av=*(const float4*)&As[k][ty*4];
      float4 bv=*(const float4*)&Bs[k][tx*4];
      MM4x4(av,bv);
    }
    __syncthreads();
  }
  #pragma unroll
  for (int i=0;i<4;++i){
    int c=m0+ty*4+i;
    size_t base=(size_t)((b<<7)+c)*4096 + n0+tx*4;
    float4 xv=*(const float4*)&x1[base];
    float4 v=make_float4(acc[i][0]+xv.x,acc[i][1]+xv.y,acc[i][2]+xv.z,acc[i][3]+xv.w);
    *(float4*)&mamba[base]=v;
  }
}

// K12: per (b,c): sum / sumsq / max over HW
__global__ __launch_bounds__(256) void k_stats(const float* __restrict__ mamba, float* __restrict__ stats){
  const int bc=blockIdx.x, tid=threadIdx.x;
  const float* row=mamba+(size_t)bc*4096;
  float s=0.f,s2=0.f,mx=-3.402823466e38f;
  for (int i=tid;i<4096;i+=256){ float v=row[i]; s+=v; s2=fmaf(v,v,s2); mx=fmaxf(mx,v); }
  #pragma unroll
  for (int m=1;m<64;m<<=1){
    s+=__shfl_xor(s,m); s2+=__shfl_xor(s2,m); mx=fmaxf(mx,__shfl_xor(mx,m));
  }
  __shared__ float r0[4],r1[4],r2[4];
  if ((tid&63)==0){ int wv=tid>>6; r0[wv]=s; r1[wv]=s2; r2[wv]=mx; }
  __syncthreads();
  if (tid==0){
    stats[bc*3+0]=r0[0]+r0[1]+r0[2]+r0[3];
    stats[bc*3+1]=r1[0]+r1[1]+r1[2]+r1[3];
    stats[bc*3+2]=fmaxf(fmaxf(r2[0],r2[1]),fmaxf(r2[2],r2[3]));
  }
}

// K13: channel-attention MLP + group-norm stats
__global__ __launch_bounds__(256) void k_att(const float* __restrict__ stats,
    const float* __restrict__ fc1, const float* __restrict__ fc2,
    float* __restrict__ att, float* __restrict__ gstat){
  __shared__ float avg[2][128], mxs[2][128], S1[2][128], S2[2][128], hsum[2][8], attv[2][128];
  const int tid=threadIdx.x, b=tid>>7, c=tid&127;
  float s1=stats[tid*3], s2=stats[tid*3+1], m=stats[tid*3+2];
  avg[b][c]=s1*(1.f/4096.f); mxs[b][c]=m; S1[b][c]=s1; S2[b][c]=s2;
  __syncthreads();
  if (tid<16){
    int bb=tid>>3, i=tid&7;
    float ha=0.f,hm=0.f;
    for (int cc=0;cc<128;++cc){ float w=fc1[i*128+cc]; ha=fmaf(w,avg[bb][cc],ha); hm=fmaf(w,mxs[bb][cc],hm); }
    hsum[bb][i]=fmaxf(ha,0.f)+fmaxf(hm,0.f);
  }
  __syncthreads();
  float sacc=0.f;
  #pragma unroll
  for (int i=0;i<8;++i) sacc=fmaf(fc2[c*8+i],hsum[b][i],sacc);
  float a=sigm_(sacc);
  attv[b][c]=a; att[tid]=a;
  __syncthreads();
  if (tid<4){
    int bb=tid>>1, gp=tid&1;
    float sum1=0.f,sum2=0.f;
    for (int cc=0;cc<64;++cc){
      int c2=gp*64+cc; float av=attv[bb][c2];
      sum1=fmaf(av,S1[bb][c2],sum1);
      sum2=fmaf(av*av,S2[bb][c2],sum2);
    }
    const float inv=1.f/(64.f*4096.f);
    float mu=sum1*inv, ex2=sum2*inv, var=ex2-mu*mu;
    gstat[tid*2]=mu; gstat[tid*2+1]=rsqrtf(var+1e-5f);
  }
}

// K14: out = silu(groupnorm(mamba*att)*gn_g+gn_b) + x1
__global__ __launch_bounds__(256) void k_final(const float* __restrict__ mamba,
    const float* __restrict__ x1, const float* __restrict__ att,
    const float* __restrict__ gstat, const float* __restrict__ gg,
    const float* __restrict__ gb, float* __restrict__ out){
  const int idx=blockIdx.x*256+threadIdx.x;
  const int c=(idx>>12)&127, b=idx>>19;
  const int grp=(b<<1)+(c>>6);
  float v=mamba[idx]*att[(b<<7)+c];
  float vn=(v-gstat[grp*2])*gstat[grp*2+1]*gg[c]+gb[c];
  out[idx]=silu_(vn)+x1[idx];
}

extern "C" void kernel_launch(void* const* d_in, const int* in_sizes, int n_in,
                              void* d_out, int out_size, void* d_ws, size_t ws_size,
                              hipStream_t stream){
  (void)in_sizes; (void)n_in; (void)out_size; (void)ws_size;
  const float* x        =(const float*)d_in[0];
  const float* convin_w =(const float*)d_in[1];
  const float* convin_b =(const float*)d_in[2];
  const float* ln_g     =(const float*)d_in[3];
  const float* ln_b     =(const float*)d_in[4];
  const float* in_proj_w=(const float*)d_in[5];
  const float* conv_w   =(const float*)d_in[6];
  const float* conv_b   =(const float*)d_in[7];
  const float* x_proj_w =(const float*)d_in[8];
  const float* dt_w     =(const float*)d_in[9];
  const float* dt_b     =(const float*)d_in[10];
  const float* A_logs   =(const float*)d_in[11];
  const float* Ds       =(const float*)d_in[12];
  const float* outnorm_g=(const float*)d_in[13];
  const float* outnorm_b=(const float*)d_in[14];
  const float* out_proj_w=(const float*)d_in[15];
  const float* ca_fc1_w =(const float*)d_in[16];
  const float* ca_fc2_w =(const float*)d_in[17];
  const float* gn_g     =(const float*)d_in[18];
  const float* gn_b     =(const float*)d_in[19];

  float* ws=(float*)d_ws;
  size_t off=0;
  auto alloc=[&](size_t nfloats)->float*{ float* p=ws+off; off+=(nfloats+63)&~(size_t)63; return p; };
  float* x1     =alloc(1048576);   // (B,C,L)
  float* mln    =alloc(1048576);   // (B*L,C)
  float* z      =alloc(2097152);   // (B,L,256)
  float* xmpre_t=alloc(2097152);   // (B,L,256) pre-dwconv
  float* xflat_t=alloc(2097152);   // (B,L,256) post dwconv+silu
  float* pdt    =alloc(262144);    // (bk,L,8)
  float* pbc    =alloc(1048576);   // (bk,L,32)
  float* delta_t=alloc(8388608);   // (bk,L,256)
  float* Pc     =alloc(4194304);   // (ch=128, bk*256*16)
  float* He     =alloc(4194304);
  float* Hin    =Pc;               // scanB writes Hin after reading Pc (safe alias)
  float* y4     =alloc(8388608);   // (B,L,K,256)
  float* yg     =alloc(2097152);   // (B,L,256)
  float* mamba  =alloc(1048576);   // (B,C,L)
  float* stats  =alloc(768);
  float* att    =alloc(256);
  float* gstat  =alloc(64);

  const dim3 blk(256);
  k_x1     <<<dim3(64,2,2), blk,0,stream>>>(x, convin_w, convin_b, x1);
  k_ln     <<<dim3(128,2),  blk,0,stream>>>(x1, ln_g, ln_b, mln);
  k_inproj <<<dim3(8,128),  blk,0,stream>>>(mln, in_proj_w, xmpre_t, z);
  k_dwconv <<<dim3(512),    blk,0,stream>>>(xmpre_t, conv_w, conv_b, xflat_t);
  k_proj   <<<dim3(64,5,2), blk,0,stream>>>(xflat_t, x_proj_w, pdt, pbc);
  k_delta  <<<dim3(64,4,8), blk,0,stream>>>(pdt, dt_w, dt_b, delta_t);
  k_scanA  <<<dim3(1024),   blk,0,stream>>>(delta_t, xflat_t, pbc, A_logs, Pc, He);
  k_scanB  <<<dim3(128),    blk,0,stream>>>(Pc, He, Hin);
  k_scanC  <<<dim3(1024),   blk,0,stream>>>(delta_t, xflat_t, pbc, A_logs, Ds, Hin, y4);
  k_outnorm<<<dim3(8192),   blk,0,stream>>>(y4, outnorm_g, outnorm_b, z, yg);
  k_outproj<<<dim3(64,2,2), blk,0,stream>>>(yg, out_proj_w, x1, mamba);
  k_stats  <<<dim3(256),    blk,0,stream>>>(mamba, stats);
  k_att    <<<dim3(1),      blk,0,stream>>>(stats, ca_fc1_w, ca_fc2_w, att, gstat);
  k_final  <<<dim3(4096),   blk,0,stream>>>(mamba, x1, att, gstat, gn_g, gn_b, (float*)d_out);
}